// Round 1
// baseline (844.934 us; speedup 1.0000x reference)
//
#include <hip/hip_runtime.h>

// Problem constants (fixed by setup_inputs)
#define BB 8
#define CC 64
#define HH 128
#define WW 512
#define SS 512
#define HALF 256
#define HWP (HH * WW)        // 65536
#define BHW (BB * HWP)       // 524288
#define CELLS (BB * SS * SS) // 2097152

__device__ __forceinline__ unsigned int order_f32(float f) {
    unsigned int u = __float_as_uint(f);
    return (u & 0x80000000u) ? ~u : (u | 0x80000000u);
}

// Kernel 1: project pixels, atomicMin packed (y, ~idx) key per cell.
__global__ __launch_bounds__(256) void proj_kernel(
    const float* __restrict__ camera_k,
    const float* __restrict__ depth,
    const float* __restrict__ mpp_p,
    unsigned long long* __restrict__ keys)
{
    __shared__ float sk[9];
    const int idx = blockIdx.x * 256 + threadIdx.x;   // all 256 pixels share one batch b
    const int b = idx >> 16;                          // HW = 65536

    if (threadIdx.x == 0) {
        const float rs[3] = {0.5f, 0.5f, 1.0f};
        double a[9];
        #pragma unroll
        for (int i = 0; i < 3; ++i)
            #pragma unroll
            for (int j = 0; j < 3; ++j)
                a[i*3 + j] = (double)__fmul_rn(camera_k[b*9 + i*3 + j], rs[i]);
        double det = a[0]*(a[4]*a[8]-a[5]*a[7])
                   - a[1]*(a[3]*a[8]-a[5]*a[6])
                   + a[2]*(a[3]*a[7]-a[4]*a[6]);
        double inv[9];
        inv[0] =  (a[4]*a[8]-a[5]*a[7])/det;
        inv[1] = -(a[1]*a[8]-a[2]*a[7])/det;
        inv[2] =  (a[1]*a[5]-a[2]*a[4])/det;
        inv[3] = -(a[3]*a[8]-a[5]*a[6])/det;
        inv[4] =  (a[0]*a[8]-a[2]*a[6])/det;
        inv[5] = -(a[0]*a[5]-a[2]*a[3])/det;
        inv[6] =  (a[3]*a[7]-a[4]*a[6])/det;
        inv[7] = -(a[0]*a[7]-a[1]*a[6])/det;
        inv[8] =  (a[0]*a[4]-a[1]*a[3])/det;
        #pragma unroll
        for (int i = 0; i < 9; ++i) sk[i] = (float)inv[i];
    }
    __syncthreads();

    const int rem = idx & (HWP - 1);
    const int v = rem >> 9;          // W = 512
    const int u = rem & (WW - 1);
    const float d = depth[idx];
    const float mpp = mpp_p[0];
    const float uf = (float)u, vf = (float)v;

    // Match numpy f32 semantics exactly: no FMA contraction on this chain.
    float xw = __fadd_rn(__fadd_rn(__fmul_rn(sk[0], uf), __fmul_rn(sk[1], vf)), sk[2]);
    float yw = __fadd_rn(__fadd_rn(__fmul_rn(sk[3], uf), __fmul_rn(sk[4], vf)), sk[5]);
    float zw = __fadd_rn(__fadd_rn(__fmul_rn(sk[6], uf), __fmul_rn(sk[7], vf)), sk[8]);
    float x3 = __fmul_rn(__fmul_rn(xw, d), 1.2f);
    float y3 = __fmul_rn(__fmul_rn(yw, d), 1.2f);
    float z3 = __fmul_rn(__fmul_rn(zw, d), 1.2f);

    int xi = (int)truncf(__fdiv_rn(x3, mpp));
    int zi = (int)truncf(__fdiv_rn(z3, mpp));

    if (xi >= -HALF && xi <= HALF - 1 && zi >= -HALF && zi <= HALF - 1) {
        int cell = (b << 18) | ((xi + HALF) << 9) | (zi + HALF);
        unsigned long long key =
            ((unsigned long long)order_f32(y3) << 32) | (unsigned int)(~idx);
        atomicMin(&keys[cell], key);
    }
}

// Kernel 2: transpose image (B,C,H,W) -> img_t (B, H*W, C) so that one
// cell's 64-channel gather becomes a single contiguous 256 B read.
// 64 pixels x 64 channels per block through a padded LDS tile; both the
// global read (64 consecutive pixels/lane-group) and the global write
// (64 consecutive channels) are fully coalesced; LDS is conflict-free
// ((lane+ch)%32 two-way on write, consecutive on read).
__global__ __launch_bounds__(256) void transpose_kernel(
    const float* __restrict__ img,
    float* __restrict__ img_t)
{
    __shared__ float tile[64][65];
    const int gp0  = blockIdx.x * 64;        // first global pixel (incl. batch)
    const int b    = gp0 >> 16;
    const int p0   = gp0 & (HWP - 1);
    const int lane = threadIdx.x & 63;
    const int grp  = threadIdx.x >> 6;       // 0..3

    const float* src = img + (size_t)b * CC * HWP + p0;
    #pragma unroll
    for (int i = 0; i < 16; ++i) {
        int ch = grp * 16 + i;
        tile[lane][ch] = src[(size_t)ch * HWP + lane];
    }
    __syncthreads();
    float* dst = img_t + (size_t)gp0 * CC;
    #pragma unroll
    for (int i = 0; i < 16; ++i) {
        int p = grp * 16 + i;
        dst[(size_t)p * CC + lane] = tile[p][lane];
    }
}

// Kernel 3: scatter. Block = 128 consecutive cells (same b, xx; zz run).
// Phase 0: load the block's 128 keys once (vs 16x re-read before).
// Phase 1: per cell, the wave reads all 64 channels as ONE contiguous
//          256 B load from img_t (4 fully-used lines vs ~64 scattered
//          lines in the old per-channel gather), into an XOR-swizzled
//          LDS tile (store col = ch ^ (cell&31): permutation of 0..63
//          per row -> 2-way, free).
// Phase 2: channel-major coalesced writes; LDS read col = c ^ (l&31)
//          hits all 32 banks (2-way, free).
__global__ __launch_bounds__(256) void scatter_kernel(
    const float* __restrict__ img_t,
    const unsigned long long* __restrict__ keys,
    float* __restrict__ out)
{
    __shared__ float sT[128 * 64];
    __shared__ int   sRem[128];

    const int cell0 = blockIdx.x * 128;
    const int b     = cell0 >> 18;
    const int t     = threadIdx.x;
    const int w     = t >> 6;     // wave 0..3
    const int l     = t & 63;     // lane

    if (t < 128) {
        unsigned long long k = keys[cell0 + t];
        sRem[t] = (k == ~0ull) ? -1
                : (int)((~(unsigned int)(k & 0xFFFFFFFFull)) & (HWP - 1));
    }
    __syncthreads();

    const size_t bHWP = (size_t)b * HWP;
    #pragma unroll 8
    for (int i = 0; i < 32; ++i) {
        int cell = w * 32 + i;
        int r = sRem[cell];               // wave-uniform broadcast
        float val = 0.0f;
        if (r >= 0)                       // uniform branch
            val = img_t[((bHWP + (size_t)r) << 6) + l];
        sT[(cell << 6) + (l ^ (cell & 31))] = val;
    }
    __syncthreads();

    const int local = cell0 & (SS * SS - 1);
    float* op = out + (size_t)b * CC * (SS * SS) + local;
    #pragma unroll
    for (int j = 0; j < 16; ++j) {
        int c = w * 16 + j;
        float v0 = sT[((l)      << 6) + (c ^ (l & 31))];
        float v1 = sT[((l + 64) << 6) + (c ^ (l & 31))];
        float* oc = op + (size_t)c * (SS * SS);
        oc[l]      = v0;                  // 256 B coalesced per wave
        oc[64 + l] = v1;
    }
}

extern "C" void kernel_launch(void* const* d_in, const int* in_sizes, int n_in,
                              void* d_out, int out_size, void* d_ws, size_t ws_size,
                              hipStream_t stream) {
    const float* img      = (const float*)d_in[0];
    const float* camera_k = (const float*)d_in[1];
    const float* depth    = (const float*)d_in[2];
    const float* mpp      = (const float*)d_in[3];

    unsigned long long* keys = (unsigned long long*)d_ws;
    // img_t after keys (16 MiB), 32 MiB-aligned offset; needs 128 MiB more.
    float* img_t = (float*)((char*)d_ws + ((size_t)32 << 20));

    // Empty-cell sentinel = 0xFFFF.. (no finite y maps to it).
    hipMemsetAsync(keys, 0xFF, (size_t)CELLS * sizeof(unsigned long long), stream);

    transpose_kernel<<<BHW / 64, 256, 0, stream>>>(img, img_t);
    proj_kernel<<<BHW / 256, 256, 0, stream>>>(camera_k, depth, mpp, keys);
    scatter_kernel<<<CELLS / 128, 256, 0, stream>>>(img_t, keys, (float*)d_out);
}